// Round 2
// baseline (131.044 us; speedup 1.0000x reference)
//
#include <hip/hip_runtime.h>
#include <math.h>

#define BB   8
#define NN   96
#define DD   16
#define H0D  50
#define H1D  50
#define OUTD 64
#define IT   16     // i-rows per block
#define TILES 6     // NN / IT
#define XP   17     // padded stride for 16-wide rows
#define DP   97     // padded stride for 96-wide rows

// W1: (51,50): rows 0-15 Wxi, 16-31 Wxj, 32-47 Wxk, 48 w_ij, 49 w_jk, 50 w_ik
// W2: (83,50): rows 0-15 xi, 16-31 xj, 32 dis, 33-82 m3
// W3: (66,64)

__global__ __launch_bounds__(256) void sgc_fused(
    const float* __restrict__ x, const float* __restrict__ adj,
    const float* __restrict__ W1, const float* __restrict__ b1,
    const float* __restrict__ W2, const float* __restrict__ b2,
    const float* __restrict__ W3, const float* __restrict__ b3,
    float* __restrict__ out)
{
    const int b  = blockIdx.x / TILES;
    const int i0 = (blockIdx.x % TILES) * IT;
    const int tid  = threadIdx.x;
    const int wv   = tid >> 6;
    const int lane = tid & 63;

    __shared__ float sx[NN * XP];                  // x[b]
    __shared__ unsigned long long smask[NN][2];    // adjacency bitmask per row
    __shared__ float snx[NN * XP];                 // nx[j] = sum_{k in nbr(j)} x_k
    __shared__ float sdeg[NN], ssdjk[NN];
    __shared__ float sP[NN * H0D];                 // deg_j*Bm[j,h] + sumC[j,h]
    __shared__ float sA[IT * H0D];                 // A rows for this tile
    __shared__ float sdisI[IT * DP];               // dis rows for this tile
    __shared__ float ssdik[IT * DP];               // sd_ik for this tile
    __shared__ float smsum[IT * H0D];
    __shared__ float sm2s[IT * H1D];

    // ---- stage x[b]; build adjacency bitmasks (coalesced + ballot) ----
    for (int t = tid; t < NN * DD; t += 256)
        sx[(t >> 4) * XP + (t & 15)] = x[(size_t)b * NN * DD + t];
    for (int j = wv; j < NN; j += 4) {
        const float* arow = adj + ((size_t)b * NN + j) * NN;
        unsigned long long m0 = __ballot(arow[lane] != 0.f);
        float v1 = (lane < NN - 64) ? arow[64 + lane] : 0.f;
        unsigned long long m1 = __ballot(v1 != 0.f);
        if (lane == 0) { smask[j][0] = m0; smask[j][1] = m1; }
    }
    __syncthreads();

    // ---- per-batch: deg, sdjk (dis recomputed on the fly); nx; tile A, disI ----
    if (tid < NN) {
        const int j = tid;
        unsigned long long m0 = smask[j][0], m1 = smask[j][1];
        float dg = (float)(__popcll(m0) + __popcll(m1));
        float sd = 0.f;
        const float* xj = &sx[j * XP];
        unsigned long long mm = m0; int base = 0;
        for (int half = 0; half < 2; ++half) {
            while (mm) {
                int k = base + __ffsll((unsigned long long)mm) - 1;
                mm &= mm - 1;
                const float* xk = &sx[k * XP];
                float s = 1e-10f;
                #pragma unroll
                for (int d = 0; d < DD; ++d) { float t = xj[d] - xk[d]; s += t * t; }
                sd += sqrtf(s);
            }
            mm = m1; base = 64;
        }
        sdeg[j] = dg; ssdjk[j] = sd;
    }
    for (int t = tid; t < NN * DD; t += 256) {
        int j = t >> 4, d = t & 15;
        unsigned long long m0 = smask[j][0], m1 = smask[j][1];
        float s = 0.f;
        while (m0) { int k = __ffsll((unsigned long long)m0) - 1; m0 &= m0 - 1; s += sx[k * XP + d]; }
        while (m1) { int k = 64 + __ffsll((unsigned long long)m1) - 1; m1 &= m1 - 1; s += sx[k * XP + d]; }
        snx[j * XP + d] = s;
    }
    for (int t = tid; t < IT * H0D; t += 256) {
        int ii = t / H0D, h = t % H0D;
        const float* xi = &sx[(i0 + ii) * XP];
        float s = 0.f;
        #pragma unroll
        for (int d = 0; d < DD; ++d) s += xi[d] * W1[d * H0D + h];
        sA[t] = s;
    }
    for (int t = tid; t < IT * NN; t += 256) {
        int ii = t / NN, k = t % NN;
        const float* xi = &sx[(i0 + ii) * XP];
        const float* xk = &sx[k * XP];
        float s = 1e-10f;
        #pragma unroll
        for (int d = 0; d < DD; ++d) { float tt = xi[d] - xk[d]; s += tt * tt; }
        sdisI[ii * DP + k] = sqrtf(s);
    }
    __syncthreads();

    // ---- P[j,h] = deg_j*(x_j@Wxj)[h] + (nx_j@Wxk)[h];  sdik for the tile ----
    for (int t = tid; t < NN * H0D; t += 256) {
        int j = t / H0D, h = t % H0D;
        float dg = sdeg[j];
        const float* xj = &sx[j * XP];
        const float* nj = &snx[j * XP];
        float s = 0.f;
        #pragma unroll
        for (int d = 0; d < DD; ++d)
            s += dg * xj[d] * W1[(DD + d) * H0D + h] + nj[d] * W1[(2 * DD + d) * H0D + h];
        sP[t] = s;
    }
    for (int t = tid; t < IT * NN; t += 256) {
        int ii = t / NN, j = t % NN;
        unsigned long long m0 = smask[j][0], m1 = smask[j][1];
        const float* di = &sdisI[ii * DP];
        float s = 0.f;
        while (m0) { int k = __ffsll((unsigned long long)m0) - 1; m0 &= m0 - 1; s += di[k]; }
        while (m1) { int k = 64 + __ffsll((unsigned long long)m1) - 1; m1 &= m1 - 1; s += di[k]; }
        ssdik[ii * DP + j] = s;
    }
    __syncthreads();

    // ---- neighbor accumulation: wave = one i, lane = channel h (wave-uniform mask walk) ----
    const int hl = (lane < H0D) ? lane : 0;
    float b1l = 0.f, wij = 0.f, wjk = 0.f, wik = 0.f;
    if (lane < H0D) {
        b1l = b1[lane];
        wij = W1[(3 * DD + 0) * H0D + lane];
        wjk = W1[(3 * DD + 1) * H0D + lane];
        wik = W1[(3 * DD + 2) * H0D + lane];
    }
    for (int r = 0; r < IT / 4; ++r) {
        const int ii = r * 4 + wv;
        const int i  = i0 + ii;
        const float ab = sA[ii * H0D + hl] + b1l;
        float msum = 0.f;
        unsigned long long mm = smask[i][0]; int base = 0;
        for (int half = 0; half < 2; ++half) {
            while (mm) {
                int j = base + __ffsll((unsigned long long)mm) - 1;
                mm &= mm - 1;
                float S = sdeg[j] * (ab + sdisI[ii * DP + j] * wij)
                        + sP[j * H0D + hl]
                        + ssdjk[j] * wjk + ssdik[ii * DP + j] * wik;
                msum += (S >= 0.f) ? S : 0.05f * S;
            }
            mm = smask[i][1]; base = 64;
        }
        if (lane < H0D) smsum[ii * H0D + lane] = msum;
    }
    __syncthreads();

    // ---- layer 2: m2_sum = leaky(agg @ W2 + deg_i*b2) ----
    for (int t = tid; t < IT * H1D; t += 256) {
        int ii = t / H1D, h = t % H1D;
        int i = i0 + ii;
        float dg = sdeg[i];
        float s = dg * b2[h];
        const float* xi = &sx[i * XP];
        const float* ni = &snx[i * XP];
        #pragma unroll
        for (int d = 0; d < DD; ++d)
            s += dg * xi[d] * W2[d * H1D + h] + ni[d] * W2[(DD + d) * H1D + h];
        s += ssdjk[i] * W2[(2 * DD) * H1D + h];
        const float* ms = &smsum[ii * H0D];
        for (int c = 0; c < H0D; ++c)
            s += ms[c] * W2[(2 * DD + 1 + c) * H1D + h];
        sm2s[t] = (s >= 0.f) ? s : 0.05f * s;
    }
    __syncthreads();

    // ---- layer 3 + store ----
    for (int t = tid; t < IT * OUTD; t += 256) {
        int ii = t >> 6, o = t & 63;
        int i = i0 + ii;
        float s = b3[o];
        const float* xi = &sx[i * XP];
        #pragma unroll
        for (int d = 0; d < DD; ++d) s += xi[d] * W3[d * OUTD + o];
        const float* m2 = &sm2s[ii * H1D];
        for (int h = 0; h < H1D; ++h) s += m2[h] * W3[(DD + h) * OUTD + o];
        s = (s >= 0.f) ? s : 0.05f * s;
        out[((size_t)(b * NN + i)) * OUTD + o] = s;
    }
}

extern "C" void kernel_launch(void* const* d_in, const int* in_sizes, int n_in,
                              void* d_out, int out_size, void* d_ws, size_t ws_size,
                              hipStream_t stream) {
    const float* x   = (const float*)d_in[0];
    const float* adj = (const float*)d_in[1];
    const float* W1  = (const float*)d_in[2];
    const float* b1  = (const float*)d_in[3];
    const float* W2  = (const float*)d_in[4];
    const float* b2  = (const float*)d_in[5];
    const float* W3  = (const float*)d_in[6];
    const float* b3  = (const float*)d_in[7];
    float* out = (float*)d_out;

    sgc_fused<<<BB * TILES, 256, 0, stream>>>(x, adj, W1, b1, W2, b2, W3, b3, out);
}

// Round 3
// 84.068 us; speedup vs baseline: 1.5588x; 1.5588x over previous
//
#include <hip/hip_runtime.h>
#include <math.h>

#define BB   8
#define NN   96
#define DD   16
#define H0D  50
#define H1D  50
#define OUTD 64
#define XP   17

typedef unsigned long long u64;

// W1: (51,50): rows 0-15 Wxi, 16-31 Wxj, 32-47 Wxk, 48 w_ij, 49 w_jk, 50 w_ik
// W2: (83,50): rows 0-15 xi, 16-31 xj, 32 dis, 33-82 m3
// W3: (66,64)

__device__ __forceinline__ float wave_reduce_sum(float v) {
    #pragma unroll
    for (int off = 1; off < 64; off <<= 1)
        v += __shfl_xor(v, off, 64);
    return v;
}

// ---- kernel A: one wave per (b, j) -----------------------------------------
__global__ __launch_bounds__(64) void kA(
    const float* __restrict__ x, const float* __restrict__ adj,
    const float* __restrict__ W1,
    float* __restrict__ disws, u64* __restrict__ maskws,
    float* __restrict__ degws, float* __restrict__ sdjkws,
    float* __restrict__ nxws, float* __restrict__ APws)
{
    const int b = blockIdx.x / NN, j = blockIdx.x % NN;
    const int lane = threadIdx.x;
    __shared__ float sx[NN * XP];
    __shared__ float snx[DD];

    // stage x[b] (float4, coalesced)
    const float4* x4 = (const float4*)(x + (size_t)b * NN * DD);
    #pragma unroll
    for (int t = lane; t < NN * DD / 4; t += 64) {
        float4 v = x4[t];
        int row = t >> 2, d = (t & 3) * 4;
        float* p = &sx[row * XP + d];
        p[0] = v.x; p[1] = v.y; p[2] = v.z; p[3] = v.w;
    }
    // adjacency bitmask for row j (adj values are exactly 0/1)
    const float* arow = adj + ((size_t)b * NN + j) * NN;
    float a0 = arow[lane];
    float a1 = (lane < NN - 64) ? arow[64 + lane] : 0.f;
    u64 m0 = __ballot(a0 != 0.f);
    u64 m1 = __ballot(a1 != 0.f);
    __syncthreads();

    // dis row j (lane = k, two rounds)
    const float* xj = &sx[j * XP];
    float d0, d1 = 0.f;
    {
        float s = 1e-10f;
        const float* xk = &sx[lane * XP];
        #pragma unroll
        for (int d = 0; d < DD; ++d) { float t = xj[d] - xk[d]; s += t * t; }
        d0 = sqrtf(s);
    }
    if (lane < NN - 64) {
        float s = 1e-10f;
        const float* xk = &sx[(64 + lane) * XP];
        #pragma unroll
        for (int d = 0; d < DD; ++d) { float t = xj[d] - xk[d]; s += t * t; }
        d1 = sqrtf(s);
    }
    float* drow = disws + ((size_t)b * NN + j) * NN;
    drow[lane] = d0;
    if (lane < NN - 64) drow[64 + lane] = d1;

    float deg = (float)(__popcll(m0) + __popcll(m1));
    float part = (((m0 >> lane) & 1) ? d0 : 0.f)
               + ((lane < 32 && ((m1 >> lane) & 1)) ? d1 : 0.f);
    float sdjk = wave_reduce_sum(part);
    if (lane == 0) {
        degws[b * NN + j]  = deg;
        sdjkws[b * NN + j] = sdjk;
        maskws[(b * NN + j) * 2 + 0] = m0;
        maskws[(b * NN + j) * 2 + 1] = m1;
    }

    // nx_j[d] = sum_{k in nbr(j)} x_k[d]; lane = d + 16*chunk, 24 k's per chunk
    {
        int c = lane >> 4, d = lane & 15;
        unsigned sm;
        if (c == 0)      sm = (unsigned)(m0 & 0xFFFFFFu);
        else if (c == 1) sm = (unsigned)((m0 >> 24) & 0xFFFFFFu);
        else if (c == 2) sm = (unsigned)((m0 >> 48) & 0xFFFFu) | ((unsigned)(m1 & 0xFFu) << 16);
        else             sm = (unsigned)((m1 >> 8) & 0xFFFFFFu);
        float s = 0.f;
        int base = c * 24;
        while (sm) {
            int k = base + __ffs(sm) - 1;
            sm &= sm - 1;
            s += sx[k * XP + d];
        }
        s += __shfl_xor(s, 16, 64);
        s += __shfl_xor(s, 32, 64);
        if (lane < DD) {
            snx[lane] = s;
            nxws[(b * NN + j) * DD + lane] = s;
        }
    }
    __syncthreads();

    // A_j[h] = x_j@Wxi;  P_j[h] = deg_j*(x_j@Wxj)[h] + (nx_j@Wxk)[h]
    if (lane < H0D) {
        float a = 0.f, bm = 0.f, sc = 0.f;
        #pragma unroll
        for (int d = 0; d < DD; ++d) {
            float xv = xj[d];
            a  += xv * W1[d * H0D + lane];
            bm += xv * W1[(DD + d) * H0D + lane];
            sc += snx[d] * W1[(2 * DD + d) * H0D + lane];
        }
        float* ap = APws + ((size_t)b * NN + j) * 128;
        ap[lane]      = a;
        ap[64 + lane] = deg * bm + sc;
    }
}

// ---- kernel B: one wave per (b, i) -----------------------------------------
__global__ __launch_bounds__(64) void kB(
    const float* __restrict__ x,
    const float* __restrict__ W1, const float* __restrict__ b1,
    const float* __restrict__ W2, const float* __restrict__ b2,
    const float* __restrict__ W3, const float* __restrict__ b3,
    const float* __restrict__ disws, const u64* __restrict__ maskws,
    const float* __restrict__ degws, const float* __restrict__ sdjkws,
    const float* __restrict__ nxws, const float* __restrict__ APws,
    float* __restrict__ out)
{
    const int b = blockIdx.x / NN, i = blockIdx.x % NN;
    const int lane = threadIdx.x;
    __shared__ u64 sm0[NN], sm1[NN];
    __shared__ float sdis[NN], sdeg[NN], ssdjk[NN], ssdik[NN];
    __shared__ float smsum[H0D], sm2[H1D], sxi[DD], snxi[DD];

    const ulonglong2* mp = (const ulonglong2*)(maskws + (size_t)b * NN * 2);
    #pragma unroll
    for (int t = lane; t < NN; t += 64) {
        ulonglong2 m = mp[t];
        sm0[t] = m.x; sm1[t] = m.y;
    }
    const float* drow = disws + ((size_t)b * NN + i) * NN;
    sdis[lane] = drow[lane];
    if (lane < 32) sdis[64 + lane] = drow[64 + lane];
    sdeg[lane] = degws[b * NN + lane];
    if (lane < 32) sdeg[64 + lane] = degws[b * NN + 64 + lane];
    ssdjk[lane] = sdjkws[b * NN + lane];
    if (lane < 32) ssdjk[64 + lane] = sdjkws[b * NN + 64 + lane];
    if (lane < DD) {
        sxi[lane]  = x[((size_t)b * NN + i) * DD + lane];
        snxi[lane] = nxws[(b * NN + i) * DD + lane];
    }
    __syncthreads();

    // sd_ik[i,j] = sum_{k in nbr(j)} dis[i,k]; lane = j (two rounds)
    {
        u64 mm0 = sm0[lane], mm1 = sm1[lane];
        float s = 0.f;
        while (mm0) { int k = __ffsll(mm0) - 1;      mm0 &= mm0 - 1; s += sdis[k]; }
        while (mm1) { int k = 64 + __ffsll(mm1) - 1; mm1 &= mm1 - 1; s += sdis[k]; }
        ssdik[lane] = s;
        if (lane < 32) {
            int j = 64 + lane;
            u64 n0 = sm0[j], n1 = sm1[j];
            float t = 0.f;
            while (n0) { int k = __ffsll(n0) - 1;      n0 &= n0 - 1; t += sdis[k]; }
            while (n1) { int k = 64 + __ffsll(n1) - 1; n1 &= n1 - 1; t += sdis[k]; }
            ssdik[j] = t;
        }
    }
    __syncthreads();

    // neighbor accumulation: lane = channel h, wave-uniform mask walk
    {
        const int h = (lane < H0D) ? lane : 0;
        float ab  = APws[((size_t)b * NN + i) * 128 + h] + b1[h];
        float wij = W1[(3 * DD + 0) * H0D + h];
        float wjk = W1[(3 * DD + 1) * H0D + h];
        float wik = W1[(3 * DD + 2) * H0D + h];
        float msum = 0.f;
        u64 mm = sm0[i]; int base = 0;
        for (int half = 0; half < 2; ++half) {
            while (mm) {
                int j = base + __ffsll(mm) - 1;
                mm &= mm - 1;
                float S = sdeg[j] * (ab + sdis[j] * wij)
                        + APws[((size_t)b * NN + j) * 128 + 64 + h]
                        + ssdjk[j] * wjk + ssdik[j] * wik;
                msum += (S >= 0.f) ? S : 0.05f * S;
            }
            mm = sm1[i]; base = 64;
        }
        if (lane < H0D) smsum[lane] = msum;
    }
    __syncthreads();

    // layer 2
    const float degi = sdeg[i], sdjki = ssdjk[i];
    if (lane < H1D) {
        float s = degi * b2[lane];
        #pragma unroll
        for (int d = 0; d < DD; ++d)
            s += degi * sxi[d] * W2[d * H1D + lane]
               + snxi[d] * W2[(DD + d) * H1D + lane];
        s += sdjki * W2[(2 * DD) * H1D + lane];
        for (int c = 0; c < H0D; ++c)
            s += smsum[c] * W2[(2 * DD + 1 + c) * H1D + lane];
        sm2[lane] = (s >= 0.f) ? s : 0.05f * s;
    }
    __syncthreads();

    // layer 3 + store (lane = output channel)
    {
        float s = b3[lane];
        #pragma unroll
        for (int d = 0; d < DD; ++d) s += sxi[d] * W3[d * OUTD + lane];
        for (int h = 0; h < H1D; ++h) s += sm2[h] * W3[(DD + h) * OUTD + lane];
        s = (s >= 0.f) ? s : 0.05f * s;
        out[((size_t)b * NN + i) * OUTD + lane] = s;
    }
}

extern "C" void kernel_launch(void* const* d_in, const int* in_sizes, int n_in,
                              void* d_out, int out_size, void* d_ws, size_t ws_size,
                              hipStream_t stream) {
    const float* x   = (const float*)d_in[0];
    const float* adj = (const float*)d_in[1];
    const float* W1  = (const float*)d_in[2];
    const float* b1  = (const float*)d_in[3];
    const float* W2  = (const float*)d_in[4];
    const float* b2  = (const float*)d_in[5];
    const float* W3  = (const float*)d_in[6];
    const float* b3  = (const float*)d_in[7];
    float* out = (float*)d_out;

    // ws layout: masks (u64, 8B-aligned) first, then floats
    u64*   maskws = (u64*)d_ws;                        // 8*96*2 u64 = 12288 B
    float* fbase  = (float*)((char*)d_ws + BB * NN * 2 * sizeof(u64));
    float* disws  = fbase;                             // 8*96*96
    float* degws  = disws + BB * NN * NN;              // 768
    float* sdjkws = degws + BB * NN;                   // 768
    float* nxws   = sdjkws + BB * NN;                  // 8*96*16
    float* APws   = nxws + BB * NN * DD;               // 8*96*128

    kA<<<BB * NN, 64, 0, stream>>>(x, adj, W1, disws, maskws, degws, sdjkws, nxws, APws);
    kB<<<BB * NN, 64, 0, stream>>>(x, W1, b1, W2, b2, W3, b3,
                                   disws, maskws, degws, sdjkws, nxws, APws, out);
}